// Round 9
// baseline (129.316 us; speedup 1.0000x reference)
//
#include <hip/hip_runtime.h>
#include <math.h>

#define BB    4
#define MM    1024
#define NN    1024
#define DD    9
#define KSEL  16
#define NROW  (BB * MM)      // 4096 rows per phase
#define NBLKD (2 * NROW / 4) // 2048 dist blocks (blocks 0..1023 intra, rest outer)
#define MAGIC 0x13579BDFu    // done-flag value (!= 0xAAAAAAAA poison)

// Workspace. yT first => 16B-aligned float4 planes. done[]/ticket need no
// zeroing: done uses MAGIC vs poison; ticket zeroed by statsprep (stream-
// ordered before dist). Cross-block data inside a kernel is accessed via
// atomic RMW (cross-XCD coherent); cross-kernel data relies on dispatch-
// boundary cache flush (validated R1-R8).
struct Ws {
  float yT[BB * DD * NN];   // [b][p][j] SoA planes
  float qy[BB * NN];        // y_j^T Cinv y_j
  float bpart[NBLKD];       // per-dist-block partial ([0,1024)=intra)
  float part[16][55];       // per-stats-block moment partials
  unsigned done[16];        // statsprep flag barrier
  unsigned ticket;          // dist last-block ticket
  float cnt;
  float mean[DD];
  float cinv[DD * DD];
};

// ---------------------------------------------------------------------------
// Kernel 1: 16 blocks x 256. Phase A: per-block masked moment partials ->
// global + magic done-flag; spin on all 16 flags (blocks co-resident; RMW
// reads coherent). Phase B: every block re-reads partials via RMW, sums in
// fp64, runs the fully-unrolled register-resident fp64 Gauss-Jordan (lane p
// owns augmented row p; cov of ~2048 N(0,1) samples is SPD, diag~1 => no
// pivoting, pinv == inverse), then writes qy + SoA transpose for its 256
// y_pred rows. Block 0 publishes cnt/mean/cinv and zeroes dist's ticket.
// ---------------------------------------------------------------------------
__global__ __launch_bounds__(256) void statsprep_kernel(
    const float* __restrict__ outputs, const float* __restrict__ targets,
    const int* __restrict__ mask, Ws* __restrict__ ws) {
  const int g = blockIdx.x;
  const int tid = threadIdx.x;
  if (g == 0 && tid == 0) ws->ticket = 0u;

  // --- Phase A: this block's moment partials ------------------------------
  const int r = g * 256 + tid;
  float acc[55];
#pragma unroll
  for (int k = 0; k < 55; ++k) acc[k] = 0.f;
  if (mask[r] != 0) {
    float t[DD];
#pragma unroll
    for (int k = 0; k < DD; ++k) t[k] = targets[r * DD + k];
    acc[0] = 1.f;
#pragma unroll
    for (int k = 0; k < DD; ++k) acc[1 + k] = t[k];
    int u = 10;
#pragma unroll
    for (int p = 0; p < DD; ++p)
#pragma unroll
      for (int q = p; q < DD; ++q) acc[u++] = t[p] * t[q];
  }
  __shared__ float lds[4][55];
#pragma unroll
  for (int k = 0; k < 55; ++k) {
    float v = acc[k];
#pragma unroll
    for (int off = 32; off > 0; off >>= 1) v += __shfl_down(v, off, 64);
    if ((tid & 63) == 0) lds[tid >> 6][k] = v;
  }
  __syncthreads();
  if (tid < 55)
    ws->part[g][tid] = lds[0][tid] + lds[1][tid] + lds[2][tid] + lds[3][tid];
  __threadfence();  // device-scope release of part[g][*]
  __syncthreads();
  if (tid == 0) atomicExch(&ws->done[g], MAGIC);

  // --- flag barrier: wait for all 16 blocks' partials ---------------------
  if (tid < 16) {
    while (atomicAdd(&ws->done[tid], 0u) != MAGIC) {
    }
  }
  __syncthreads();

  // --- Phase B: fp64 sum (RMW reads => coherent) + inverse ----------------
  __shared__ double Sd[55];
  __shared__ float Cs[DD * DD];
  if (tid < 55) {
    double s = 0.0;
#pragma unroll
    for (int b = 0; b < 16; ++b)
      s += (double)atomicAdd(&ws->part[b][tid], 0.f);
    Sd[tid] = s;
  }
  __syncthreads();

  if (tid < 64) {
    const double cnt = Sd[0];
    const int p = (tid < DD) ? tid : 0;  // junk lanes mirror row 0
    double row[2 * DD];
    {
      const double mu_p = Sd[1 + p] / cnt;
#pragma unroll
      for (int q = 0; q < DD; ++q) {
        const int pp = (p < q) ? p : q;
        const int qq = (p < q) ? q : p;
        const int idx = 10 + 9 * pp - (pp * (pp - 1)) / 2 + (qq - pp);
        row[q] = (Sd[idx] - cnt * mu_p * (Sd[1 + q] / cnt)) / (cnt - 1.0);
        row[DD + q] = (p == q) ? 1.0 : 0.0;
      }
    }
#pragma unroll
    for (int c = 0; c < DD; ++c) {
      const double diag = __shfl(row[c], c, 64);
      const double dinv = 1.0 / diag;
      if (tid == c) {
#pragma unroll
        for (int q = 0; q < 2 * DD; ++q) row[q] *= dinv;
      }
      const double f = (tid == c) ? 0.0 : row[c];
#pragma unroll
      for (int q = 0; q < 2 * DD; ++q) {
        const double pv = __shfl(row[q], c, 64);
        row[q] -= f * pv;
      }
    }
    if (tid < DD) {
#pragma unroll
      for (int q = 0; q < DD; ++q) {
        const float cf = (float)row[DD + q];
        Cs[tid * DD + q] = cf;
        if (g == 0) ws->cinv[tid * DD + q] = cf;
      }
    }
    if (tid == 0 && g == 0) {
      ws->cnt = (float)cnt;
#pragma unroll
      for (int q = 0; q < DD; ++q) ws->mean[q] = (float)(Sd[1 + q] / cnt);
    }
  }
  __syncthreads();

  // --- qy + SoA transpose for this block's 256 rows -----------------------
  const int j = g * 256 + tid;
  const int b = j >> 10;
  const int jj = j & (NN - 1);
  float y[DD];
#pragma unroll
  for (int k = 0; k < DD; ++k) y[k] = outputs[j * DD + k];
  float q = 0.f;
#pragma unroll
  for (int p = 0; p < DD; ++p) {
    float s = 0.f;
#pragma unroll
    for (int t = 0; t < DD; ++t) s += Cs[p * DD + t] * y[t];
    q += y[p] * s;
    ws->yT[(b * DD + p) * NN + jj] = y[p];
  }
  ws->qy[j] = q;
}

// ---------------------------------------------------------------------------
// Sum of the 16 smallest of the wave's 1024 values: per-lane bitonic sort +
// 6 shfl_xor half-cleaner rounds (re-merge skipped after the last: the
// half-cleaner output already holds the top-16 multiset; order irrelevant).
// ---------------------------------------------------------------------------
__device__ __forceinline__ float topk16_sum(float v[16]) {
#pragma unroll
  for (int k = 2; k <= 16; k <<= 1) {
#pragma unroll
    for (int j = k >> 1; j > 0; j >>= 1) {
#pragma unroll
      for (int i = 0; i < 16; ++i) {
        const int l = i ^ j;
        if (l > i) {
          const bool up = ((i & k) == 0);
          const float lo = fminf(v[i], v[l]);
          const float hi = fmaxf(v[i], v[l]);
          v[i] = up ? lo : hi;
          v[l] = up ? hi : lo;
        }
      }
    }
  }
#pragma unroll
  for (int off = 1; off < 64; off <<= 1) {
    float pr[16];
#pragma unroll
    for (int i = 0; i < 16; ++i) pr[i] = __shfl_xor(v[i], off, 64);
#pragma unroll
    for (int i = 0; i < 16; ++i) v[i] = fminf(v[i], pr[15 - i]);
    if (off < 32) {
#pragma unroll
      for (int j = 8; j > 0; j >>= 1) {
#pragma unroll
        for (int i = 0; i < 16; ++i) {
          const int l = i ^ j;
          if (l > i) {
            const float lo = fminf(v[i], v[l]);
            const float hi = fmaxf(v[i], v[l]);
            v[i] = lo;
            v[l] = hi;
          }
        }
      }
    }
  }
  float t = v[0];
#pragma unroll
  for (int k = 1; k < 16; ++k) t += v[k];
  return t;
}

// ---------------------------------------------------------------------------
// Kernel 2: R6's verified dist body (one wave per row-slot, 8192 waves) +
// R8's verified ticket finalize. Blocks 0..1023 intra, 1024..2047 outer
// (phase uniform per block). Coalesced float4 loads from SoA planes; per-
// block partial to a distinct slot; last block reduces via RMW reads.
// ---------------------------------------------------------------------------
__global__ __launch_bounds__(256) void dist_kernel(
    const float* __restrict__ outputs, const float* __restrict__ targets,
    const int* __restrict__ mask, Ws* __restrict__ ws,
    float* __restrict__ out) {
  const int wv = threadIdx.x >> 6;
  const int lane = threadIdx.x & 63;
  const int s = blockIdx.x * 4 + wv;
  const bool is_intra = (s < NROW);
  const int r = s & (NROW - 1);
  const int b = r >> 10;

  float total = 0.f;
  if (!(is_intra && mask[r] == 0)) {
    float a[DD];
    if (is_intra) {
#pragma unroll
      for (int k = 0; k < DD; ++k) a[k] = targets[r * DD + k] - ws->mean[k];
    } else {
#pragma unroll
      for (int k = 0; k < DD; ++k) a[k] = outputs[r * DD + k] + ws->mean[k];
    }
    float w9[DD];
    float qa = 0.f;
#pragma unroll
    for (int p = 0; p < DD; ++p) {
      float acc = 0.f;
#pragma unroll
      for (int t = 0; t < DD; ++t) acc += ws->cinv[p * DD + t] * a[t];
      w9[p] = acc;
      qa += a[p] * acc;
    }

    float v[16];
#pragma unroll
    for (int k = 0; k < 16; ++k) v[k] = 0.f;
    const float* __restrict__ yTb = ws->yT + (size_t)b * DD * NN;
#pragma unroll
    for (int p = 0; p < DD; ++p) {
      const float4* __restrict__ pl = (const float4*)(yTb + (size_t)p * NN);
      const float wp = w9[p];
#pragma unroll
      for (int c = 0; c < 4; ++c) {
        const float4 y4 = pl[c * 64 + lane];
        v[c * 4 + 0] += wp * y4.x;
        v[c * 4 + 1] += wp * y4.y;
        v[c * 4 + 2] += wp * y4.z;
        v[c * 4 + 3] += wp * y4.w;
      }
    }
    {
      const float4* __restrict__ q4 = (const float4*)(ws->qy + (size_t)b * NN);
#pragma unroll
      for (int c = 0; c < 4; ++c) {
        const float4 qv = q4[c * 64 + lane];
        v[c * 4 + 0] = qa + qv.x - 2.f * v[c * 4 + 0];
        v[c * 4 + 1] = qa + qv.y - 2.f * v[c * 4 + 1];
        v[c * 4 + 2] = qa + qv.z - 2.f * v[c * 4 + 2];
        v[c * 4 + 3] = qa + qv.w - 2.f * v[c * 4 + 3];
      }
    }
    total = topk16_sum(v);
  }

  __shared__ float bsum[4];
  __shared__ int s_last;
  if (lane == 0) bsum[wv] = total;
  __syncthreads();
  if (threadIdx.x == 0) {
    ws->bpart[blockIdx.x] = bsum[0] + bsum[1] + bsum[2] + bsum[3];
    __threadfence();
    const unsigned t = atomicAdd(&ws->ticket, 1u);
    s_last = (t == NBLKD - 1) ? 1 : 0;
  }
  __syncthreads();

  if (s_last) {
    double li = 0.0, lo = 0.0;
    for (int k = threadIdx.x; k < NBLKD; k += 256) {
      const double pv = (double)atomicAdd(&ws->bpart[k], 0.f);  // coherent RMW
      if (k < NBLKD / 2) li += pv; else lo += pv;
    }
#pragma unroll
    for (int off = 32; off > 0; off >>= 1) {
      li += __shfl_down(li, off, 64);
      lo += __shfl_down(lo, off, 64);
    }
    __shared__ double ri[4], ro[4];
    if (lane == 0) { ri[wv] = li; ro[wv] = lo; }
    __syncthreads();
    if (threadIdx.x == 0) {
      const double si = ri[0] + ri[1] + ri[2] + ri[3];
      const double so = ro[0] + ro[1] + ro[2] + ro[3];
      const float intra = (float)(si / (double)ws->cnt);
      const float outer = (float)(so / (double)(NROW * KSEL));
      out[0] = intra;
      out[1] = intra;
      out[2] = outer;
    }
  }
}

extern "C" void kernel_launch(void* const* d_in, const int* in_sizes, int n_in,
                              void* d_out, int out_size, void* d_ws,
                              size_t ws_size, hipStream_t stream) {
  const float* outputs = (const float*)d_in[0];  // (4,1024,9) f32
  const float* targets = (const float*)d_in[1];  // (4,1024,9) f32
  const int* mask = (const int*)d_in[2];         // (4,1024)
  Ws* ws = (Ws*)d_ws;
  float* out = (float*)d_out;

  statsprep_kernel<<<16, 256, 0, stream>>>(outputs, targets, mask, ws);
  dist_kernel<<<NBLKD, 256, 0, stream>>>(outputs, targets, mask, ws, out);
}

// Round 10
// 111.491 us; speedup vs baseline: 1.1599x; 1.1599x over previous
//
#include <hip/hip_runtime.h>
#include <math.h>

#define BB    4
#define MM    1024
#define NN    1024
#define DD    9
#define KSEL  16
#define NROW  (BB * MM)      // 4096 rows per phase
#define NBLKD (2 * NROW / 4) // 2048 dist blocks; 0..1023 intra, 1024..2047 outer

// Workspace. yT first => 16B-aligned float4 planes. ticket zeroed by
// stats_kernel (stream-ordered before dist). bpart published via device-scope
// atomicExch (coherence point) -- NO per-block __threadfence (R9 lesson:
// per-block fence == L2-writeback storm, +26 us).
struct Ws {
  float yT[BB * DD * NN];   // [b][p][j] SoA planes
  float qy[BB * NN];        // y_j^T Cinv y_j
  float bpart[NBLKD];       // per-dist-block partial ([0,1024)=intra)
  float part[16][55];       // per-stats-block moment partials
  float cnt;
  float mean[DD];
  float cinv[DD * DD];
  unsigned ticket;          // dist last-block ticket
};

// ---------------------------------------------------------------------------
// Kernel 1: 16 blocks x 256, one target row/thread. 55 masked moment partials
// -> wave shuffle reduce -> LDS across waves -> part[block][k]. Block 0 also
// zeroes the dist ticket (stream-ordered ahead of dist; R8-validated).
// ---------------------------------------------------------------------------
__global__ __launch_bounds__(256) void stats_kernel(
    const float* __restrict__ targets, const int* __restrict__ mask,
    Ws* __restrict__ ws) {
  const int tid = threadIdx.x;
  const int r = blockIdx.x * 256 + tid;
  if (blockIdx.x == 0 && tid == 0) ws->ticket = 0u;

  float acc[55];
#pragma unroll
  for (int k = 0; k < 55; ++k) acc[k] = 0.f;
  if (mask[r] != 0) {
    float t[DD];
#pragma unroll
    for (int k = 0; k < DD; ++k) t[k] = targets[r * DD + k];
    acc[0] = 1.f;
#pragma unroll
    for (int k = 0; k < DD; ++k) acc[1 + k] = t[k];
    int u = 10;
#pragma unroll
    for (int p = 0; p < DD; ++p)
#pragma unroll
      for (int q = p; q < DD; ++q) acc[u++] = t[p] * t[q];
  }

  __shared__ float lds[4][55];
#pragma unroll
  for (int k = 0; k < 55; ++k) {
    float v = acc[k];
#pragma unroll
    for (int off = 32; off > 0; off >>= 1) v += __shfl_down(v, off, 64);
    if ((tid & 63) == 0) lds[tid >> 6][k] = v;
  }
  __syncthreads();
  if (tid < 55)
    ws->part[blockIdx.x][tid] =
        lds[0][tid] + lds[1][tid] + lds[2][tid] + lds[3][tid];
}

// ---------------------------------------------------------------------------
// Kernel 2 (R6-verified): 16 blocks x 256. Wave 0 of EVERY block redundantly
// sums the 16 partials (fp64) and runs the fully-unrolled register-resident
// fp64 Gauss-Jordan (lane p owns augmented row p; cov of ~2048 N(0,1)
// samples is SPD, diag~1 => no pivoting, pinv == inverse); broadcasts via
// LDS; then all threads write qy + SoA transpose. Block 0 publishes
// cnt/mean/cinv.
// ---------------------------------------------------------------------------
__global__ __launch_bounds__(256) void prep_kernel(
    const float* __restrict__ outputs, Ws* __restrict__ ws) {
  const int tid = threadIdx.x;
  __shared__ double Sd[55];
  __shared__ float Cs[DD * DD];

  if (tid < 55) {
    double s = 0.0;
#pragma unroll
    for (int b = 0; b < 16; ++b) s += (double)ws->part[b][tid];
    Sd[tid] = s;
  }
  __syncthreads();

  if (tid < 64) {
    const double cnt = Sd[0];
    const int p = (tid < DD) ? tid : 0;  // junk lanes mirror row 0
    double row[2 * DD];
    {
      const double mu_p = Sd[1 + p] / cnt;
#pragma unroll
      for (int q = 0; q < DD; ++q) {
        const int pp = (p < q) ? p : q;
        const int qq = (p < q) ? q : p;
        const int idx = 10 + 9 * pp - (pp * (pp - 1)) / 2 + (qq - pp);
        row[q] = (Sd[idx] - cnt * mu_p * (Sd[1 + q] / cnt)) / (cnt - 1.0);
        row[DD + q] = (p == q) ? 1.0 : 0.0;
      }
    }
#pragma unroll
    for (int c = 0; c < DD; ++c) {
      const double diag = __shfl(row[c], c, 64);
      const double dinv = 1.0 / diag;
      if (tid == c) {
#pragma unroll
        for (int q = 0; q < 2 * DD; ++q) row[q] *= dinv;
      }
      const double f = (tid == c) ? 0.0 : row[c];
#pragma unroll
      for (int q = 0; q < 2 * DD; ++q) {
        const double pv = __shfl(row[q], c, 64);
        row[q] -= f * pv;
      }
    }
    if (tid < DD) {
#pragma unroll
      for (int q = 0; q < DD; ++q) {
        const float cf = (float)row[DD + q];
        Cs[tid * DD + q] = cf;
        if (blockIdx.x == 0) ws->cinv[tid * DD + q] = cf;
      }
    }
    if (tid == 0 && blockIdx.x == 0) {
      ws->cnt = (float)cnt;
#pragma unroll
      for (int q = 0; q < DD; ++q) ws->mean[q] = (float)(Sd[1 + q] / cnt);
    }
  }
  __syncthreads();

  const int j = blockIdx.x * 256 + tid;
  const int b = j >> 10;
  const int jj = j & (NN - 1);
  float y[DD];
#pragma unroll
  for (int k = 0; k < DD; ++k) y[k] = outputs[j * DD + k];
  float q = 0.f;
#pragma unroll
  for (int p = 0; p < DD; ++p) {
    float s = 0.f;
#pragma unroll
    for (int t = 0; t < DD; ++t) s += Cs[p * DD + t] * y[t];
    q += y[p] * s;
    ws->yT[(b * DD + p) * NN + jj] = y[p];
  }
  ws->qy[j] = q;
}

// ---------------------------------------------------------------------------
// Sum of the 16 smallest of the wave's 1024 values: per-lane bitonic sort +
// 6 shfl_xor half-cleaner rounds (re-merge skipped after the last: output
// already holds the top-16 multiset; order irrelevant for a sum).
// ---------------------------------------------------------------------------
__device__ __forceinline__ float topk16_sum(float v[16]) {
#pragma unroll
  for (int k = 2; k <= 16; k <<= 1) {
#pragma unroll
    for (int j = k >> 1; j > 0; j >>= 1) {
#pragma unroll
      for (int i = 0; i < 16; ++i) {
        const int l = i ^ j;
        if (l > i) {
          const bool up = ((i & k) == 0);
          const float lo = fminf(v[i], v[l]);
          const float hi = fmaxf(v[i], v[l]);
          v[i] = up ? lo : hi;
          v[l] = up ? hi : lo;
        }
      }
    }
  }
#pragma unroll
  for (int off = 1; off < 64; off <<= 1) {
    float pr[16];
#pragma unroll
    for (int i = 0; i < 16; ++i) pr[i] = __shfl_xor(v[i], off, 64);
#pragma unroll
    for (int i = 0; i < 16; ++i) v[i] = fminf(v[i], pr[15 - i]);
    if (off < 32) {
#pragma unroll
      for (int j = 8; j > 0; j >>= 1) {
#pragma unroll
        for (int i = 0; i < 16; ++i) {
          const int l = i ^ j;
          if (l > i) {
            const float lo = fminf(v[i], v[l]);
            const float hi = fmaxf(v[i], v[l]);
            v[i] = lo;
            v[l] = hi;
          }
        }
      }
    }
  }
  float t = v[0];
#pragma unroll
  for (int k = 1; k < 16; ++k) t += v[k];
  return t;
}

// ---------------------------------------------------------------------------
// Kernel 3: R6's verified dist body (one wave per row-slot, 8192 waves) +
// FENCE-FREE ticket finalize: block partial published with device-scope
// atomicExch (performed at the coherence point -- no L2 writeback); the
// ticket increment is data-dependent on the exch's returned value (opaque
// asm tie) so it cannot be issued before the partial is globally performed.
// Last block reads partials via RMW atomics (coherent; R8/R9-validated).
// ---------------------------------------------------------------------------
__global__ __launch_bounds__(256) void dist_kernel(
    const float* __restrict__ outputs, const float* __restrict__ targets,
    const int* __restrict__ mask, Ws* __restrict__ ws,
    float* __restrict__ out) {
  const int wv = threadIdx.x >> 6;
  const int lane = threadIdx.x & 63;
  const int s = blockIdx.x * 4 + wv;
  const bool is_intra = (s < NROW);  // block-uniform (4 | 4096)
  const int r = s & (NROW - 1);
  const int b = r >> 10;

  float total = 0.f;
  if (!(is_intra && mask[r] == 0)) {
    float a[DD];
    if (is_intra) {
#pragma unroll
      for (int k = 0; k < DD; ++k) a[k] = targets[r * DD + k] - ws->mean[k];
    } else {
#pragma unroll
      for (int k = 0; k < DD; ++k) a[k] = outputs[r * DD + k] + ws->mean[k];
    }
    float w9[DD];
    float qa = 0.f;
#pragma unroll
    for (int p = 0; p < DD; ++p) {
      float acc = 0.f;
#pragma unroll
      for (int t = 0; t < DD; ++t) acc += ws->cinv[p * DD + t] * a[t];
      w9[p] = acc;
      qa += a[p] * acc;
    }

    float v[16];
#pragma unroll
    for (int k = 0; k < 16; ++k) v[k] = 0.f;
    const float* __restrict__ yTb = ws->yT + (size_t)b * DD * NN;
#pragma unroll
    for (int p = 0; p < DD; ++p) {
      const float4* __restrict__ pl = (const float4*)(yTb + (size_t)p * NN);
      const float wp = w9[p];
#pragma unroll
      for (int c = 0; c < 4; ++c) {
        const float4 y4 = pl[c * 64 + lane];
        v[c * 4 + 0] += wp * y4.x;
        v[c * 4 + 1] += wp * y4.y;
        v[c * 4 + 2] += wp * y4.z;
        v[c * 4 + 3] += wp * y4.w;
      }
    }
    {
      const float4* __restrict__ q4 = (const float4*)(ws->qy + (size_t)b * NN);
#pragma unroll
      for (int c = 0; c < 4; ++c) {
        const float4 qv = q4[c * 64 + lane];
        v[c * 4 + 0] = qa + qv.x - 2.f * v[c * 4 + 0];
        v[c * 4 + 1] = qa + qv.y - 2.f * v[c * 4 + 1];
        v[c * 4 + 2] = qa + qv.z - 2.f * v[c * 4 + 2];
        v[c * 4 + 3] = qa + qv.w - 2.f * v[c * 4 + 3];
      }
    }
    total = topk16_sum(v);
  }

  __shared__ float bsum[4];
  __shared__ int s_last;
  if (lane == 0) bsum[wv] = total;
  __syncthreads();
  if (threadIdx.x == 0) {
    const float sblk = bsum[0] + bsum[1] + bsum[2] + bsum[3];
    // Publish at the coherence point; returned old value (poison) creates
    // the ordering dependency for the ticket increment.
    const float old = atomicExch(&ws->bpart[blockIdx.x], sblk);
    unsigned inc = 1u;
    asm volatile("" : "+v"(inc) : "v"(old));  // inc "depends" on exch result
    const unsigned t = atomicAdd(&ws->ticket, inc);
    s_last = (t == NBLKD - 1) ? 1 : 0;
  }
  __syncthreads();

  if (s_last) {
    double li = 0.0, lo = 0.0;
    for (int k = threadIdx.x; k < NBLKD; k += 256) {
      const double pv = (double)atomicAdd(&ws->bpart[k], 0.f);  // coherent RMW
      if (k < NBLKD / 2) li += pv; else lo += pv;
    }
#pragma unroll
    for (int off = 32; off > 0; off >>= 1) {
      li += __shfl_down(li, off, 64);
      lo += __shfl_down(lo, off, 64);
    }
    __shared__ double ri[4], ro[4];
    if (lane == 0) { ri[wv] = li; ro[wv] = lo; }
    __syncthreads();
    if (threadIdx.x == 0) {
      const double si = ri[0] + ri[1] + ri[2] + ri[3];
      const double so = ro[0] + ro[1] + ro[2] + ro[3];
      const float intra = (float)(si / (double)ws->cnt);
      const float outer = (float)(so / (double)(NROW * KSEL));
      out[0] = intra;
      out[1] = intra;
      out[2] = outer;
    }
  }
}

extern "C" void kernel_launch(void* const* d_in, const int* in_sizes, int n_in,
                              void* d_out, int out_size, void* d_ws,
                              size_t ws_size, hipStream_t stream) {
  const float* outputs = (const float*)d_in[0];  // (4,1024,9) f32
  const float* targets = (const float*)d_in[1];  // (4,1024,9) f32
  const int* mask = (const int*)d_in[2];         // (4,1024)
  Ws* ws = (Ws*)d_ws;
  float* out = (float*)d_out;

  stats_kernel<<<NROW / 256, 256, 0, stream>>>(targets, mask, ws);
  prep_kernel<<<(BB * NN) / 256, 256, 0, stream>>>(outputs, ws);
  dist_kernel<<<NBLKD, 256, 0, stream>>>(outputs, targets, mask, ws, out);
}

// Round 11
// 105.445 us; speedup vs baseline: 1.2264x; 1.0573x over previous
//
#include <hip/hip_runtime.h>
#include <math.h>

#define BB    4
#define MM    1024
#define NN    1024
#define DD    9
#define KSEL  16
#define NROW  (BB * MM)      // 4096 rows per phase
#define NSLOT (2 * NROW)
#define NBLKD (NSLOT / 4)    // 2048 dist blocks, 4 waves (row-slots) each

// Workspace. yT first => 16B-aligned float4 planes. Every field written
// before read each call (masked rows write rowsum=0) => no memset, no
// atomics anywhere. R8-R10 lesson: in-kernel cross-block finalize (fence or
// atomic ticket) always loses to a separate 1-block finalize node.
struct Ws {
  float yT[BB * DD * NN];   // [b][p][j] SoA planes
  float qy[BB * NN];        // y_j^T Cinv y_j
  float rowsum[NSLOT];      // per-row top-16 sum
  float cnt;
  float mean[DD];
  float cinv[DD * DD];
};

// ---------------------------------------------------------------------------
// Kernel 1: 16 blocks x 256. Each block REDUNDANTLY computes the full masked
// moments (grid-stride over all 4096 target rows; input is L2/L3-hot, so the
// 16x redundancy is ~free and removes the stats kernel + its partials
// round-trip + one graph node). Wave 0 then runs the fully-unrolled
// register-resident fp64 Gauss-Jordan (lane p owns augmented row p; cov of
// ~2048 N(0,1) samples is SPD, diag~1 => no pivoting, pinv == inverse);
// broadcast via LDS; all threads write qy + SoA transpose. Block 0 publishes
// cnt/mean/cinv for dist/finalize.
// ---------------------------------------------------------------------------
__global__ __launch_bounds__(256) void prep_kernel(
    const float* __restrict__ outputs, const float* __restrict__ targets,
    const int* __restrict__ mask, Ws* __restrict__ ws) {
  const int tid = threadIdx.x;
  __shared__ float lds[4][55];
  __shared__ double Sd[55];
  __shared__ float Cs[DD * DD];

  // --- full masked moments, redundant per block ---------------------------
  float acc[55];
#pragma unroll
  for (int k = 0; k < 55; ++k) acc[k] = 0.f;
#pragma unroll
  for (int it = 0; it < NROW / 256; ++it) {
    const int r = it * 256 + tid;
    if (mask[r] != 0) {
      float t[DD];
#pragma unroll
      for (int k = 0; k < DD; ++k) t[k] = targets[r * DD + k];
      acc[0] += 1.f;
#pragma unroll
      for (int k = 0; k < DD; ++k) acc[1 + k] += t[k];
      int u = 10;
#pragma unroll
      for (int p = 0; p < DD; ++p)
#pragma unroll
        for (int q = p; q < DD; ++q) acc[u++] += t[p] * t[q];
    }
  }
#pragma unroll
  for (int k = 0; k < 55; ++k) {
    float v = acc[k];
#pragma unroll
    for (int off = 32; off > 0; off >>= 1) v += __shfl_down(v, off, 64);
    if ((tid & 63) == 0) lds[tid >> 6][k] = v;
  }
  __syncthreads();
  if (tid < 55)
    Sd[tid] = (double)lds[0][tid] + (double)lds[1][tid] + (double)lds[2][tid] +
              (double)lds[3][tid];
  __syncthreads();

  // --- 9x9 fp64 inverse on wave 0 -----------------------------------------
  if (tid < 64) {
    const double cnt = Sd[0];
    const int p = (tid < DD) ? tid : 0;  // junk lanes mirror row 0
    double row[2 * DD];
    {
      const double mu_p = Sd[1 + p] / cnt;
#pragma unroll
      for (int q = 0; q < DD; ++q) {
        const int pp = (p < q) ? p : q;
        const int qq = (p < q) ? q : p;
        const int idx = 10 + 9 * pp - (pp * (pp - 1)) / 2 + (qq - pp);
        row[q] = (Sd[idx] - cnt * mu_p * (Sd[1 + q] / cnt)) / (cnt - 1.0);
        row[DD + q] = (p == q) ? 1.0 : 0.0;
      }
    }
#pragma unroll
    for (int c = 0; c < DD; ++c) {
      const double diag = __shfl(row[c], c, 64);
      const double dinv = 1.0 / diag;
      if (tid == c) {
#pragma unroll
        for (int q = 0; q < 2 * DD; ++q) row[q] *= dinv;
      }
      const double f = (tid == c) ? 0.0 : row[c];
#pragma unroll
      for (int q = 0; q < 2 * DD; ++q) {
        const double pv = __shfl(row[q], c, 64);
        row[q] -= f * pv;
      }
    }
    if (tid < DD) {
#pragma unroll
      for (int q = 0; q < DD; ++q) {
        const float cf = (float)row[DD + q];
        Cs[tid * DD + q] = cf;
        if (blockIdx.x == 0) ws->cinv[tid * DD + q] = cf;
      }
    }
    if (tid == 0 && blockIdx.x == 0) {
      ws->cnt = (float)cnt;
#pragma unroll
      for (int q = 0; q < DD; ++q) ws->mean[q] = (float)(Sd[1 + q] / cnt);
    }
  }
  __syncthreads();

  // --- qy + SoA transpose for this block's 256 y_pred rows ----------------
  const int j = blockIdx.x * 256 + tid;
  const int b = j >> 10;
  const int jj = j & (NN - 1);
  float y[DD];
#pragma unroll
  for (int k = 0; k < DD; ++k) y[k] = outputs[j * DD + k];
  float q = 0.f;
#pragma unroll
  for (int p = 0; p < DD; ++p) {
    float s = 0.f;
#pragma unroll
    for (int t = 0; t < DD; ++t) s += Cs[p * DD + t] * y[t];
    q += y[p] * s;
    ws->yT[(b * DD + p) * NN + jj] = y[p];
  }
  ws->qy[j] = q;
}

// ---------------------------------------------------------------------------
// Sum of the 16 smallest of the wave's 1024 values: per-lane bitonic sort +
// 6 shfl_xor half-cleaner rounds (re-merge skipped after the last: output
// already holds the top-16 multiset; order irrelevant for a sum).
// ---------------------------------------------------------------------------
__device__ __forceinline__ float topk16_sum(float v[16]) {
#pragma unroll
  for (int k = 2; k <= 16; k <<= 1) {
#pragma unroll
    for (int j = k >> 1; j > 0; j >>= 1) {
#pragma unroll
      for (int i = 0; i < 16; ++i) {
        const int l = i ^ j;
        if (l > i) {
          const bool up = ((i & k) == 0);
          const float lo = fminf(v[i], v[l]);
          const float hi = fmaxf(v[i], v[l]);
          v[i] = up ? lo : hi;
          v[l] = up ? hi : lo;
        }
      }
    }
  }
#pragma unroll
  for (int off = 1; off < 64; off <<= 1) {
    float pr[16];
#pragma unroll
    for (int i = 0; i < 16; ++i) pr[i] = __shfl_xor(v[i], off, 64);
#pragma unroll
    for (int i = 0; i < 16; ++i) v[i] = fminf(v[i], pr[15 - i]);
    if (off < 32) {
#pragma unroll
      for (int j = 8; j > 0; j >>= 1) {
#pragma unroll
        for (int i = 0; i < 16; ++i) {
          const int l = i ^ j;
          if (l > i) {
            const float lo = fminf(v[i], v[l]);
            const float hi = fmaxf(v[i], v[l]);
            v[i] = lo;
            v[l] = hi;
          }
        }
      }
    }
  }
  float t = v[0];
#pragma unroll
  for (int k = 1; k < 16; ++k) t += v[k];
  return t;
}

// ---------------------------------------------------------------------------
// Kernel 2 (R6-verified body, untouched): one wave per row-slot, 4 waves/
// block; no LDS sync, no atomics. Coalesced float4 loads from the SoA
// planes; lane 0 stores rowsum[s].
// ---------------------------------------------------------------------------
__global__ __launch_bounds__(256) void dist_kernel(
    const float* __restrict__ outputs, const float* __restrict__ targets,
    const int* __restrict__ mask, Ws* __restrict__ ws) {
  const int wv = threadIdx.x >> 6;
  const int lane = threadIdx.x & 63;
  const int s = blockIdx.x * 4 + wv;
  const bool is_intra = (s < NROW);  // wave-uniform
  const int r = s & (NROW - 1);
  const int b = r >> 10;

  if (is_intra && mask[r] == 0) {
    if (lane == 0) ws->rowsum[s] = 0.f;
    return;
  }

  float a[DD];
  if (is_intra) {
#pragma unroll
    for (int k = 0; k < DD; ++k) a[k] = targets[r * DD + k] - ws->mean[k];
  } else {
#pragma unroll
    for (int k = 0; k < DD; ++k) a[k] = outputs[r * DD + k] + ws->mean[k];
  }
  float w9[DD];
  float qa = 0.f;
#pragma unroll
  for (int p = 0; p < DD; ++p) {
    float acc = 0.f;
#pragma unroll
    for (int t = 0; t < DD; ++t) acc += ws->cinv[p * DD + t] * a[t];
    w9[p] = acc;
    qa += a[p] * acc;
  }

  float v[16];
#pragma unroll
  for (int k = 0; k < 16; ++k) v[k] = 0.f;
  const float* __restrict__ yTb = ws->yT + (size_t)b * DD * NN;
#pragma unroll
  for (int p = 0; p < DD; ++p) {
    const float4* __restrict__ pl = (const float4*)(yTb + (size_t)p * NN);
    const float wp = w9[p];
#pragma unroll
    for (int c = 0; c < 4; ++c) {
      const float4 y4 = pl[c * 64 + lane];
      v[c * 4 + 0] += wp * y4.x;
      v[c * 4 + 1] += wp * y4.y;
      v[c * 4 + 2] += wp * y4.z;
      v[c * 4 + 3] += wp * y4.w;
    }
  }
  {
    const float4* __restrict__ q4 = (const float4*)(ws->qy + (size_t)b * NN);
#pragma unroll
    for (int c = 0; c < 4; ++c) {
      const float4 qv = q4[c * 64 + lane];
      v[c * 4 + 0] = qa + qv.x - 2.f * v[c * 4 + 0];
      v[c * 4 + 1] = qa + qv.y - 2.f * v[c * 4 + 1];
      v[c * 4 + 2] = qa + qv.z - 2.f * v[c * 4 + 2];
      v[c * 4 + 3] = qa + qv.w - 2.f * v[c * 4 + 3];
    }
  }

  const float total = topk16_sum(v);
  if (lane == 0) ws->rowsum[s] = total;
}

// ---------------------------------------------------------------------------
// Kernel 3 (R6-verified): one block; reduce 8192 row sums -> three scalars.
// ---------------------------------------------------------------------------
__global__ __launch_bounds__(256) void finalize_kernel(
    const Ws* __restrict__ ws, float* __restrict__ out) {
  const int tid = threadIdx.x;
  double li = 0.0, lo = 0.0;
  for (int k = tid; k < NROW; k += 256) {
    li += (double)ws->rowsum[k];
    lo += (double)ws->rowsum[NROW + k];
  }
#pragma unroll
  for (int off = 32; off > 0; off >>= 1) {
    li += __shfl_down(li, off, 64);
    lo += __shfl_down(lo, off, 64);
  }
  __shared__ double lds_i[4], lds_o[4];
  if ((tid & 63) == 0) {
    lds_i[tid >> 6] = li;
    lds_o[tid >> 6] = lo;
  }
  __syncthreads();
  if (tid == 0) {
    const double si = lds_i[0] + lds_i[1] + lds_i[2] + lds_i[3];
    const double so = lds_o[0] + lds_o[1] + lds_o[2] + lds_o[3];
    const float intra = (float)(si / (double)ws->cnt);
    const float outer = (float)(so / (double)(NROW * KSEL));
    out[0] = intra;
    out[1] = intra;
    out[2] = outer;
  }
}

extern "C" void kernel_launch(void* const* d_in, const int* in_sizes, int n_in,
                              void* d_out, int out_size, void* d_ws,
                              size_t ws_size, hipStream_t stream) {
  const float* outputs = (const float*)d_in[0];  // (4,1024,9) f32
  const float* targets = (const float*)d_in[1];  // (4,1024,9) f32
  const int* mask = (const int*)d_in[2];         // (4,1024)
  Ws* ws = (Ws*)d_ws;
  float* out = (float*)d_out;

  prep_kernel<<<16, 256, 0, stream>>>(outputs, targets, mask, ws);
  dist_kernel<<<NBLKD, 256, 0, stream>>>(outputs, targets, mask, ws);
  finalize_kernel<<<1, 256, 0, stream>>>(ws, out);
}